// Round 14
// baseline (269.680 us; speedup 1.0000x reference)
//
#include <hip/hip_runtime.h>
#include <hip/hip_bf16.h>

#define D_MODEL 1024
#define N_HEADS 16
#define HEAD_DIM 64
#define BATCH 4
#define SEQ 2048
#define M_ROWS (BATCH * SEQ)  // 8192

typedef __attribute__((ext_vector_type(8))) __bf16 bf16x8;
typedef __attribute__((ext_vector_type(8))) short short8;
typedef __attribute__((ext_vector_type(4))) float f32x4;

static __device__ __forceinline__ unsigned short f2bf_rne(float f) {
  unsigned int u = __float_as_uint(f);
  u += 0x7FFFu + ((u >> 16) & 1u);
  return (unsigned short)(u >> 16);
}

#if __has_builtin(__builtin_amdgcn_exp2f)
#define EXP2F(x) __builtin_amdgcn_exp2f(x)
#else
#define EXP2F(x) exp2f(x)
#endif

static __device__ __forceinline__ void gl_lds16(const unsigned short* g, unsigned short* l) {
  __builtin_amdgcn_global_load_lds((const __attribute__((address_space(1))) unsigned int*)g,
                                   (__attribute__((address_space(3))) unsigned int*)l, 16, 0, 0);
}

// ---------------- merged fp32 -> bf16 conversion (x + 4 weights), one launch ----------------
__global__ __launch_bounds__(256) void cvt_all(const float* __restrict__ x,
                                               const float* __restrict__ wq,
                                               const float* __restrict__ wk,
                                               const float* __restrict__ wv,
                                               const float* __restrict__ wo,
                                               unsigned short* __restrict__ xb,
                                               unsigned short* __restrict__ wqb,
                                               unsigned short* __restrict__ wkb,
                                               unsigned short* __restrict__ wvb,
                                               unsigned short* __restrict__ wob) {
  const int bid = blockIdx.x;
  const float* src;
  unsigned short* dst;
  int i;
  if (bid < 8192) {
    src = x; dst = xb; i = bid * 256 + threadIdx.x;
  } else {
    int r = bid - 8192;
    int w = r >> 10;
    i = (r & 1023) * 256 + threadIdx.x;
    switch (w) {
      case 0: src = wq; dst = wqb; break;
      case 1: src = wk; dst = wkb; break;
      case 2: src = wv; dst = wvb; break;
      default: src = wo; dst = wob; break;
    }
  }
  float4 f = reinterpret_cast<const float4*>(src)[i];
  ushort4 o;
  o.x = f2bf_rne(f.x); o.y = f2bf_rne(f.y); o.z = f2bf_rne(f.z); o.w = f2bf_rne(f.w);
  reinterpret_cast<ushort4*>(dst)[i] = o;
}

// ---------------- fused QKV GEMM, double-buffered LDS + XOR-swizzled tiles (r13 proven) ----
__global__ __launch_bounds__(256) void qkv_gemm(const unsigned short* __restrict__ A,
                                                const unsigned short* __restrict__ Wq,
                                                const unsigned short* __restrict__ Wk,
                                                const unsigned short* __restrict__ Wv,
                                                unsigned short* __restrict__ Qo,
                                                unsigned short* __restrict__ Ko,
                                                unsigned short* __restrict__ Vt) {
  __shared__ __align__(16) unsigned short smem[16384];  // As0 Bs0 As1 Bs1, 4096 shorts each
  const int t = threadIdx.x;
  const int widx = blockIdx.x >> 3;
  const int bn = blockIdx.x & 7, bm = blockIdx.y;
  const unsigned short* Bw = (widx == 0) ? Wq : (widx == 1) ? Wk : Wv;
  const float oscale = (widx == 0) ? 0.18033688f : 1.0f;  // Q: 1/8 * log2(e)
  const int K = D_MODEL, N = D_MODEL;

  const int wave = t >> 6, lane = t & 63;
  const int wm = (wave >> 1) * 64, wn = (wave & 1) * 64;
  const int lr = lane & 15, quad = lane >> 4;
  const int rxor = (lr >> 1) & 3;  // read-side swizzle term

  const int g0 = wave * 128 + lane, g1 = g0 + 64;
  const int r0 = g0 >> 2, c0 = (((g0 & 3) ^ ((r0 >> 1) & 3)) << 3);
  const int r1 = g1 >> 2, c1 = (((g1 & 3) ^ ((r1 >> 1) & 3)) << 3);
  const unsigned short* Arow0 = A + (size_t)(bm * 128 + r0) * K + c0;
  const unsigned short* Arow1 = A + (size_t)(bm * 128 + r1) * K + c1;
  const unsigned short* Brow0 = Bw + (size_t)(bn * 128 + r0) * K + c0;
  const unsigned short* Brow1 = Bw + (size_t)(bn * 128 + r1) * K + c1;

  f32x4 acc[4][4] = {};

  gl_lds16(Arow0, &smem[g0 * 8]);
  gl_lds16(Arow1, &smem[g1 * 8]);
  gl_lds16(Brow0, &smem[4096 + g0 * 8]);
  gl_lds16(Brow1, &smem[4096 + g1 * 8]);
  __syncthreads();

  for (int it = 0; it < 32; it++) {
    const int cur = (it & 1) * 8192;
    if (it + 1 < 32) {
      const int nxt = 8192 - cur;
      const int k1 = (it + 1) * 32;
      gl_lds16(Arow0 + k1, &smem[nxt + g0 * 8]);
      gl_lds16(Arow1 + k1, &smem[nxt + g1 * 8]);
      gl_lds16(Brow0 + k1, &smem[nxt + 4096 + g0 * 8]);
      gl_lds16(Brow1 + k1, &smem[nxt + 4096 + g1 * 8]);
    }
    const unsigned short* As = &smem[cur];
    const unsigned short* Bs = &smem[cur + 4096];

    bf16x8 af[4], bfr[4];
#pragma unroll
    for (int mt = 0; mt < 4; mt++)
      af[mt] = __builtin_bit_cast(
          bf16x8,
          *reinterpret_cast<const short8*>(&As[(wm + mt * 16 + lr) * 32 + (quad ^ rxor) * 8]));
#pragma unroll
    for (int nt = 0; nt < 4; nt++)
      bfr[nt] = __builtin_bit_cast(
          bf16x8,
          *reinterpret_cast<const short8*>(&Bs[(wn + nt * 16 + lr) * 32 + (quad ^ rxor) * 8]));
#pragma unroll
    for (int mt = 0; mt < 4; mt++)
#pragma unroll
      for (int nt = 0; nt < 4; nt++)
        acc[mt][nt] = __builtin_amdgcn_mfma_f32_16x16x32_bf16(af[mt], bfr[nt], acc[mt][nt], 0, 0, 0);
    __syncthreads();
  }

  if (widx < 2) {
    unsigned short* Cp = (widx == 0) ? Qo : Ko;
#pragma unroll
    for (int mt = 0; mt < 4; mt++) {
#pragma unroll
      for (int nt = 0; nt < 4; nt++) {
        int col = bn * 128 + wn + nt * 16 + lr;
#pragma unroll
        for (int r = 0; r < 4; r++) {
          int row = bm * 128 + wm + mt * 16 + quad * 4 + r;
          Cp[(size_t)row * N + col] = f2bf_rne(acc[mt][nt][r] * oscale);
        }
      }
    }
  } else {
    // V: transpose through LDS (reuses smem), write Vt[(b*16+h2)*64+d][s]
    const int b = bm >> 4;
    const int s0 = (bm & 15) * 128;
#pragma unroll
    for (int half = 0; half < 2; half++) {
      __syncthreads();
      if ((wave & 1) == half) {
#pragma unroll
        for (int nt = 0; nt < 4; nt++) {
#pragma unroll
          for (int mt = 0; mt < 4; mt++) {
#pragma unroll
            for (int r = 0; r < 4; r++) {
              int cl = nt * 16 + lr;                 // d within this 64-col half
              int rl = wm + mt * 16 + quad * 4 + r;  // s within 128-row tile
              smem[cl * 136 + rl] = f2bf_rne(acc[mt][nt][r]);
            }
          }
        }
      }
      __syncthreads();
      const int h2 = bn * 2 + half;
      const size_t rowbase = ((size_t)(b * N_HEADS + h2)) * HEAD_DIM;
#pragma unroll
      for (int i = 0; i < 4; i++) {
        int c = i * 256 + t;
        int d = c >> 4, s8 = (c & 15) * 8;
        uint4 v = *reinterpret_cast<const uint4*>(&smem[d * 136 + s8]);
        *reinterpret_cast<uint4*>(Vt + (rowbase + d) * SEQ + s0 + s8) = v;
      }
    }
  }
}

// ---------------- O-projection GEMM, 128x64 tiles, double-buffered + XOR swizzle ----------------
__global__ __launch_bounds__(256) void gemm_bt_f32(const unsigned short* __restrict__ A,
                                                   const unsigned short* __restrict__ Bw,
                                                   float* __restrict__ Cp,
                                                   int M, int N, int K) {
  __shared__ __align__(16) unsigned short smem[12288];  // A0[4096] B0[2048] A1 B1
  const int t = threadIdx.x;
  const int bn = blockIdx.x, bm = blockIdx.y;
  const int wave = t >> 6, lane = t & 63;
  const int wm = (wave >> 1) * 64, wn = (wave & 1) * 32;
  const int lr = lane & 15, quad = lane >> 4;
  const int rxor = (lr >> 1) & 3;

  const int g0 = t, g1 = t + 256;
  const int ar0 = g0 >> 2, ac0 = (((g0 & 3) ^ ((ar0 >> 1) & 3)) << 3);
  const int ar1 = g1 >> 2, ac1 = (((g1 & 3) ^ ((ar1 >> 1) & 3)) << 3);
  const int br = t >> 2, bc = (((t & 3) ^ ((br >> 1) & 3)) << 3);
  const unsigned short* Arow0 = A + (size_t)(bm * 128 + ar0) * K + ac0;
  const unsigned short* Arow1 = A + (size_t)(bm * 128 + ar1) * K + ac1;
  const unsigned short* Brow = Bw + (size_t)(bn * 64 + br) * K + bc;

  f32x4 acc[4][2] = {};

  gl_lds16(Arow0, &smem[g0 * 8]);
  gl_lds16(Arow1, &smem[g1 * 8]);
  gl_lds16(Brow, &smem[4096 + t * 8]);
  __syncthreads();

  const int niter = K / 32;
  for (int it = 0; it < niter; it++) {
    const int cur = (it & 1) * 6144;
    if (it + 1 < niter) {
      const int nxt = 6144 - cur;
      const int k1 = (it + 1) * 32;
      gl_lds16(Arow0 + k1, &smem[nxt + g0 * 8]);
      gl_lds16(Arow1 + k1, &smem[nxt + g1 * 8]);
      gl_lds16(Brow + k1, &smem[nxt + 4096 + t * 8]);
    }
    const unsigned short* As = &smem[cur];
    const unsigned short* Bs = &smem[cur + 4096];

    bf16x8 af[4], bfr[2];
#pragma unroll
    for (int mt = 0; mt < 4; mt++)
      af[mt] = __builtin_bit_cast(
          bf16x8,
          *reinterpret_cast<const short8*>(&As[(wm + mt * 16 + lr) * 32 + (quad ^ rxor) * 8]));
#pragma unroll
    for (int nt = 0; nt < 2; nt++)
      bfr[nt] = __builtin_bit_cast(
          bf16x8,
          *reinterpret_cast<const short8*>(&Bs[(wn + nt * 16 + lr) * 32 + (quad ^ rxor) * 8]));
#pragma unroll
    for (int mt = 0; mt < 4; mt++)
#pragma unroll
      for (int nt = 0; nt < 2; nt++)
        acc[mt][nt] = __builtin_amdgcn_mfma_f32_16x16x32_bf16(af[mt], bfr[nt], acc[mt][nt], 0, 0, 0);
    __syncthreads();
  }

#pragma unroll
  for (int mt = 0; mt < 4; mt++) {
#pragma unroll
    for (int nt = 0; nt < 2; nt++) {
      int col = bn * 64 + wn + nt * 16 + lr;
#pragma unroll
      for (int r = 0; r < 4; r++) {
        int row = bm * 128 + wm + mt * 16 + quad * 4 + r;
        Cp[(size_t)row * N + col] = acc[mt][nt][r];
      }
    }
  }
}

// ---------------- causal flash attention v11: 4 waves x 32 q-rows, async XOR staging ----
// 512 blocks x 256 thr. Same grid mapping as r12 (q-tiles {p,15-p}, 34 kv-tiles uniform),
// but 4 waves x 32 q rows (2 subtiles) -> kf/vv LDS reads amortized 2x per q-row.
// r11 failed here ONLY via launch_bounds(256,4)'s 64-VGPR cap (spill); (256,2) leaves the
// allocator free (~80 needed). Async gl_lds XOR-swizzled dbuf, ONE barrier/tile (r12).
// LDS = Kv dbuf 32 KB + Ps 18 KB = 50 KB -> 3 blocks/CU.
__global__ __launch_bounds__(256, 2) void attn_causal(const unsigned short* __restrict__ Q,
                                                      const unsigned short* __restrict__ Km,
                                                      const unsigned short* __restrict__ Vt,
                                                      unsigned short* __restrict__ O) {
  __shared__ __align__(16) unsigned short Kv[2][2][64 * 64];  // [buf][K=0/V=1], unpadded
  __shared__ __align__(16) unsigned short Ps[4][32 * 72];

  const int bid = blockIdx.x;
  const int p = bid & 7;
  const int h = (bid >> 3) & 15;
  const int b = bid >> 7;

  const int t = threadIdx.x;
  const int wave = t >> 6, lane = t & 63;
  const int lr = lane & 15, quad = lane >> 4;
  const int cxor = lr & 7;

  const size_t base = (size_t)b * SEQ * D_MODEL + h * HEAD_DIM;
  const unsigned short* Qb = Q + base;
  const unsigned short* Kb = Km + base;
  const unsigned short* Vb = Vt + (size_t)(b * N_HEADS + h) * HEAD_DIM * SEQ;
  unsigned short* pw = &Ps[wave][0];

  // staging (256 thr): thread t owns chunks g0=t (rows 0..31) and g1=t+256 (rows 32..63);
  // row = g>>3, swizzled col ((g&7)^(row&7))*8; LDS offset g*16B (lane*16 contract kept).
  const int srow = t >> 3;                      // 0..31
  const int scol = ((t & 7) ^ (srow & 7)) << 3; // same for row srow+32 (32 = 0 mod 8)
  const unsigned short* Kg0 = Kb + (size_t)srow * D_MODEL + scol;
  const unsigned short* Kg1 = Kb + (size_t)(srow + 32) * D_MODEL + scol;
  const unsigned short* Vg0 = Vb + (size_t)srow * SEQ + scol;
  const unsigned short* Vg1 = Vb + (size_t)(srow + 32) * SEQ + scol;

  for (int ph = 0; ph < 2; ph++) {
    const int qt = ph ? (15 - p) : p;
    const int m0 = qt * 128 + wave * 32;
    const int ntiles = (qt + 1) * 2;

    bf16x8 qf[2][2];
#pragma unroll
    for (int s = 0; s < 2; s++)
#pragma unroll
      for (int kk = 0; kk < 2; kk++)
        qf[s][kk] = __builtin_bit_cast(
            bf16x8, *reinterpret_cast<const short8*>(
                        Qb + (size_t)(m0 + s * 16 + lr) * D_MODEL + kk * 32 + quad * 8));

    f32x4 o_acc[2][4] = {};
    float lsum[2][4] = {};

    // prologue: tile 0 -> buf 0 (async)
    gl_lds16(Kg0, &Kv[0][0][t * 8]);
    gl_lds16(Kg1, &Kv[0][0][(t + 256) * 8]);
    gl_lds16(Vg0, &Kv[0][1][t * 8]);
    gl_lds16(Vg1, &Kv[0][1][(t + 256) * 8]);

    for (int kt = 0; kt < ntiles; kt++) {
      const int cur = kt & 1;
      const int kv0 = kt * 64;
      __syncthreads();  // drains gl_lds into buf[cur]; orders buf[1-cur] reuse
      if (kt + 1 < ntiles) {  // async-stage tile kt+1 into the other buffer
        gl_lds16(Kg0 + (size_t)(kv0 + 64) * D_MODEL, &Kv[1 - cur][0][t * 8]);
        gl_lds16(Kg1 + (size_t)(kv0 + 64) * D_MODEL, &Kv[1 - cur][0][(t + 256) * 8]);
        gl_lds16(Vg0 + kv0 + 64, &Kv[1 - cur][1][t * 8]);
        gl_lds16(Vg1 + kv0 + 64, &Kv[1 - cur][1][(t + 256) * 8]);
      }
      const unsigned short* Ks = &Kv[cur][0][0];
      const unsigned short* Vs = &Kv[cur][1][0];

      // ---- QK^T: 2 subtiles x 64 kv cols (swizzled reads) ----
      f32x4 sAcc[2][4] = {};
#pragma unroll
      for (int kk = 0; kk < 2; kk++) {
        bf16x8 kf[4];
#pragma unroll
        for (int j = 0; j < 4; j++)
          kf[j] = __builtin_bit_cast(
              bf16x8, *reinterpret_cast<const short8*>(
                          &Ks[(j * 16 + lr) * 64 + ((kk * 4 + quad) ^ cxor) * 8]));
#pragma unroll
        for (int s = 0; s < 2; s++)
#pragma unroll
          for (int j = 0; j < 4; j++)
            sAcc[s][j] =
                __builtin_amdgcn_mfma_f32_16x16x32_bf16(qf[s][kk], kf[j], sAcc[s][j], 0, 0, 0);
      }

      asm volatile("s_waitcnt lgkmcnt(0)" ::: "memory");  // prev pf reads drained
#pragma unroll
      for (int s = 0; s < 2; s++) {
        const int msub = m0 + s * 16;
        const bool needmask = (kv0 + 63 > msub);  // wave-uniform
#pragma unroll
        for (int r = 0; r < 4; r++) {
          const int qpos = msub + quad * 4 + r;
          float e[4];
#pragma unroll
          for (int j = 0; j < 4; j++) e[j] = EXP2F(sAcc[s][j][r]);
          if (needmask) {
#pragma unroll
            for (int j = 0; j < 4; j++)
              if (kv0 + j * 16 + lr > qpos) e[j] = 0.f;
          }
          lsum[s][r] += (e[0] + e[1]) + (e[2] + e[3]);
          unsigned short* pr = &pw[(s * 16 + quad * 4 + r) * 72];
#pragma unroll
          for (int j = 0; j < 4; j++) pr[j * 16 + lr] = f2bf_rne(e[j]);
        }
      }
      asm volatile("s_waitcnt lgkmcnt(0)" ::: "memory");  // P writes visible (wave-lockstep)

      // ---- PV: vv shared across both subtiles (swizzled V reads) ----
#pragma unroll
      for (int kk = 0; kk < 2; kk++) {
        bf16x8 pf[2];
#pragma unroll
        for (int s = 0; s < 2; s++)
          pf[s] = __builtin_bit_cast(
              bf16x8,
              *reinterpret_cast<const short8*>(&pw[(s * 16 + lr) * 72 + kk * 32 + quad * 8]));
#pragma unroll
        for (int c = 0; c < 4; c++) {
          bf16x8 vv = __builtin_bit_cast(
              bf16x8, *reinterpret_cast<const short8*>(
                          &Vs[(c * 16 + lr) * 64 + ((kk * 4 + quad) ^ cxor) * 8]));
#pragma unroll
          for (int s = 0; s < 2; s++)
            o_acc[s][c] = __builtin_amdgcn_mfma_f32_16x16x32_bf16(pf[s], vv, o_acc[s][c], 0, 0, 0);
        }
      }
    }

    // epilogue
#pragma unroll
    for (int s = 0; s < 2; s++) {
#pragma unroll
      for (int r = 0; r < 4; r++) {
        float l = lsum[s][r];
#pragma unroll
        for (int off = 1; off < 16; off <<= 1) l += __shfl_xor(l, off, 64);
        const float inv = 1.f / l;
        const int qpos = m0 + s * 16 + quad * 4 + r;
#pragma unroll
        for (int c = 0; c < 4; c++)
          O[base + (size_t)qpos * D_MODEL + c * 16 + lr] = f2bf_rne(o_acc[s][c][r] * inv);
      }
    }
  }
}

// ---------------- launch ----------------
extern "C" void kernel_launch(void* const* d_in, const int* in_sizes, int n_in,
                              void* d_out, int out_size, void* d_ws, size_t ws_size,
                              hipStream_t stream) {
  const float* x  = (const float*)d_in[0];
  const float* Wq = (const float*)d_in[1];
  const float* Wk = (const float*)d_in[2];
  const float* Wv = (const float*)d_in[3];
  const float* Wo = (const float*)d_in[4];
  float* out = (float*)d_out;

  char* ws = (char*)d_ws;
  const size_t SZ_X = (size_t)M_ROWS * D_MODEL * 2;   // 16 MB
  const size_t SZ_W = (size_t)D_MODEL * D_MODEL * 2;  //  2 MB
  unsigned short* xb  = (unsigned short*)(ws);
  unsigned short* wqb = (unsigned short*)(ws + SZ_X);
  unsigned short* wkb = (unsigned short*)(ws + SZ_X + 1 * SZ_W);
  unsigned short* wvb = (unsigned short*)(ws + SZ_X + 2 * SZ_W);
  unsigned short* wob = (unsigned short*)(ws + SZ_X + 3 * SZ_W);
  unsigned short* Qb  = (unsigned short*)(ws + 1 * SZ_X + 4 * SZ_W);
  unsigned short* Kb  = (unsigned short*)(ws + 2 * SZ_X + 4 * SZ_W);
  unsigned short* Vt  = (unsigned short*)(ws + 3 * SZ_X + 4 * SZ_W);
  unsigned short* Ob  = xb;  // x dead after QKV projection

  cvt_all<<<12288, 256, 0, stream>>>(x, Wq, Wk, Wv, Wo, xb, wqb, wkb, wvb, wob);

  qkv_gemm<<<dim3(24, 64), 256, 0, stream>>>(xb, wqb, wkb, wvb, Qb, Kb, Vt);

  attn_causal<<<512, 256, 0, stream>>>(Qb, Kb, Vt, Ob);

  gemm_bt_f32<<<dim3(16, 64), 256, 0, stream>>>(Ob, wob, out, M_ROWS, D_MODEL, D_MODEL);
}

// Round 15
// 257.323 us; speedup vs baseline: 1.0480x; 1.0480x over previous
//
#include <hip/hip_runtime.h>
#include <hip/hip_bf16.h>

#define D_MODEL 1024
#define N_HEADS 16
#define HEAD_DIM 64
#define BATCH 4
#define SEQ 2048
#define M_ROWS (BATCH * SEQ)  // 8192

typedef __attribute__((ext_vector_type(8))) __bf16 bf16x8;
typedef __attribute__((ext_vector_type(8))) short short8;
typedef __attribute__((ext_vector_type(4))) float f32x4;

static __device__ __forceinline__ unsigned short f2bf_rne(float f) {
  unsigned int u = __float_as_uint(f);
  u += 0x7FFFu + ((u >> 16) & 1u);
  return (unsigned short)(u >> 16);
}

#if __has_builtin(__builtin_amdgcn_exp2f)
#define EXP2F(x) __builtin_amdgcn_exp2f(x)
#else
#define EXP2F(x) exp2f(x)
#endif

static __device__ __forceinline__ void gl_lds16(const unsigned short* g, unsigned short* l) {
  __builtin_amdgcn_global_load_lds((const __attribute__((address_space(1))) unsigned int*)g,
                                   (__attribute__((address_space(3))) unsigned int*)l, 16, 0, 0);
}

// ---------------- merged fp32 -> bf16 conversion (x + 4 weights), one launch ----------------
__global__ __launch_bounds__(256) void cvt_all(const float* __restrict__ x,
                                               const float* __restrict__ wq,
                                               const float* __restrict__ wk,
                                               const float* __restrict__ wv,
                                               const float* __restrict__ wo,
                                               unsigned short* __restrict__ xb,
                                               unsigned short* __restrict__ wqb,
                                               unsigned short* __restrict__ wkb,
                                               unsigned short* __restrict__ wvb,
                                               unsigned short* __restrict__ wob) {
  const int bid = blockIdx.x;
  const float* src;
  unsigned short* dst;
  int i;
  if (bid < 8192) {
    src = x; dst = xb; i = bid * 256 + threadIdx.x;
  } else {
    int r = bid - 8192;
    int w = r >> 10;
    i = (r & 1023) * 256 + threadIdx.x;
    switch (w) {
      case 0: src = wq; dst = wqb; break;
      case 1: src = wk; dst = wkb; break;
      case 2: src = wv; dst = wvb; break;
      default: src = wo; dst = wob; break;
    }
  }
  float4 f = reinterpret_cast<const float4*>(src)[i];
  ushort4 o;
  o.x = f2bf_rne(f.x); o.y = f2bf_rne(f.y); o.z = f2bf_rne(f.z); o.w = f2bf_rne(f.w);
  reinterpret_cast<ushort4*>(dst)[i] = o;
}

// ---------------- fused QKV GEMM, double-buffered LDS + XOR-swizzled tiles (r13 proven) ----
__global__ __launch_bounds__(256) void qkv_gemm(const unsigned short* __restrict__ A,
                                                const unsigned short* __restrict__ Wq,
                                                const unsigned short* __restrict__ Wk,
                                                const unsigned short* __restrict__ Wv,
                                                unsigned short* __restrict__ Qo,
                                                unsigned short* __restrict__ Ko,
                                                unsigned short* __restrict__ Vt) {
  __shared__ __align__(16) unsigned short smem[16384];  // As0 Bs0 As1 Bs1, 4096 shorts each
  const int t = threadIdx.x;
  const int widx = blockIdx.x >> 3;
  const int bn = blockIdx.x & 7, bm = blockIdx.y;
  const unsigned short* Bw = (widx == 0) ? Wq : (widx == 1) ? Wk : Wv;
  const float oscale = (widx == 0) ? 0.18033688f : 1.0f;  // Q: 1/8 * log2(e)
  const int K = D_MODEL, N = D_MODEL;

  const int wave = t >> 6, lane = t & 63;
  const int wm = (wave >> 1) * 64, wn = (wave & 1) * 64;
  const int lr = lane & 15, quad = lane >> 4;
  const int rxor = (lr >> 1) & 3;  // read-side swizzle term

  const int g0 = wave * 128 + lane, g1 = g0 + 64;
  const int r0 = g0 >> 2, c0 = (((g0 & 3) ^ ((r0 >> 1) & 3)) << 3);
  const int r1 = g1 >> 2, c1 = (((g1 & 3) ^ ((r1 >> 1) & 3)) << 3);
  const unsigned short* Arow0 = A + (size_t)(bm * 128 + r0) * K + c0;
  const unsigned short* Arow1 = A + (size_t)(bm * 128 + r1) * K + c1;
  const unsigned short* Brow0 = Bw + (size_t)(bn * 128 + r0) * K + c0;
  const unsigned short* Brow1 = Bw + (size_t)(bn * 128 + r1) * K + c1;

  f32x4 acc[4][4] = {};

  gl_lds16(Arow0, &smem[g0 * 8]);
  gl_lds16(Arow1, &smem[g1 * 8]);
  gl_lds16(Brow0, &smem[4096 + g0 * 8]);
  gl_lds16(Brow1, &smem[4096 + g1 * 8]);
  __syncthreads();

  for (int it = 0; it < 32; it++) {
    const int cur = (it & 1) * 8192;
    if (it + 1 < 32) {
      const int nxt = 8192 - cur;
      const int k1 = (it + 1) * 32;
      gl_lds16(Arow0 + k1, &smem[nxt + g0 * 8]);
      gl_lds16(Arow1 + k1, &smem[nxt + g1 * 8]);
      gl_lds16(Brow0 + k1, &smem[nxt + 4096 + g0 * 8]);
      gl_lds16(Brow1 + k1, &smem[nxt + 4096 + g1 * 8]);
    }
    const unsigned short* As = &smem[cur];
    const unsigned short* Bs = &smem[cur + 4096];

    bf16x8 af[4], bfr[4];
#pragma unroll
    for (int mt = 0; mt < 4; mt++)
      af[mt] = __builtin_bit_cast(
          bf16x8,
          *reinterpret_cast<const short8*>(&As[(wm + mt * 16 + lr) * 32 + (quad ^ rxor) * 8]));
#pragma unroll
    for (int nt = 0; nt < 4; nt++)
      bfr[nt] = __builtin_bit_cast(
          bf16x8,
          *reinterpret_cast<const short8*>(&Bs[(wn + nt * 16 + lr) * 32 + (quad ^ rxor) * 8]));
#pragma unroll
    for (int mt = 0; mt < 4; mt++)
#pragma unroll
      for (int nt = 0; nt < 4; nt++)
        acc[mt][nt] = __builtin_amdgcn_mfma_f32_16x16x32_bf16(af[mt], bfr[nt], acc[mt][nt], 0, 0, 0);
    __syncthreads();
  }

  if (widx < 2) {
    unsigned short* Cp = (widx == 0) ? Qo : Ko;
#pragma unroll
    for (int mt = 0; mt < 4; mt++) {
#pragma unroll
      for (int nt = 0; nt < 4; nt++) {
        int col = bn * 128 + wn + nt * 16 + lr;
#pragma unroll
        for (int r = 0; r < 4; r++) {
          int row = bm * 128 + wm + mt * 16 + quad * 4 + r;
          Cp[(size_t)row * N + col] = f2bf_rne(acc[mt][nt][r] * oscale);
        }
      }
    }
  } else {
    // V: transpose through LDS (reuses smem), write Vt[(b*16+h2)*64+d][s]
    const int b = bm >> 4;
    const int s0 = (bm & 15) * 128;
#pragma unroll
    for (int half = 0; half < 2; half++) {
      __syncthreads();
      if ((wave & 1) == half) {
#pragma unroll
        for (int nt = 0; nt < 4; nt++) {
#pragma unroll
          for (int mt = 0; mt < 4; mt++) {
#pragma unroll
            for (int r = 0; r < 4; r++) {
              int cl = nt * 16 + lr;                 // d within this 64-col half
              int rl = wm + mt * 16 + quad * 4 + r;  // s within 128-row tile
              smem[cl * 136 + rl] = f2bf_rne(acc[mt][nt][r]);
            }
          }
        }
      }
      __syncthreads();
      const int h2 = bn * 2 + half;
      const size_t rowbase = ((size_t)(b * N_HEADS + h2)) * HEAD_DIM;
#pragma unroll
      for (int i = 0; i < 4; i++) {
        int c = i * 256 + t;
        int d = c >> 4, s8 = (c & 15) * 8;
        uint4 v = *reinterpret_cast<const uint4*>(&smem[d * 136 + s8]);
        *reinterpret_cast<uint4*>(Vt + (rowbase + d) * SEQ + s0 + s8) = v;
      }
    }
  }
}

// ---------------- O-projection GEMM: clone of qkv K-loop, 128x128 tile, f32 out ----------------
// grid (8, 64) = 512 blocks = exactly 2 resident blocks/CU (no drain tail). Same dbuf +
// XOR swizzle as qkv (r13-proven); 16 MFMA/iter per wave (2x density of the old 128x64).
__global__ __launch_bounds__(256) void gemm_bt_f32(const unsigned short* __restrict__ A,
                                                   const unsigned short* __restrict__ Bw,
                                                   float* __restrict__ Cp,
                                                   int M, int N, int K) {
  __shared__ __align__(16) unsigned short smem[16384];
  const int t = threadIdx.x;
  const int bn = blockIdx.x, bm = blockIdx.y;
  const int wave = t >> 6, lane = t & 63;
  const int wm = (wave >> 1) * 64, wn = (wave & 1) * 64;
  const int lr = lane & 15, quad = lane >> 4;
  const int rxor = (lr >> 1) & 3;

  const int g0 = wave * 128 + lane, g1 = g0 + 64;
  const int r0 = g0 >> 2, c0 = (((g0 & 3) ^ ((r0 >> 1) & 3)) << 3);
  const int r1 = g1 >> 2, c1 = (((g1 & 3) ^ ((r1 >> 1) & 3)) << 3);
  const unsigned short* Arow0 = A + (size_t)(bm * 128 + r0) * K + c0;
  const unsigned short* Arow1 = A + (size_t)(bm * 128 + r1) * K + c1;
  const unsigned short* Brow0 = Bw + (size_t)(bn * 128 + r0) * K + c0;
  const unsigned short* Brow1 = Bw + (size_t)(bn * 128 + r1) * K + c1;

  f32x4 acc[4][4] = {};

  gl_lds16(Arow0, &smem[g0 * 8]);
  gl_lds16(Arow1, &smem[g1 * 8]);
  gl_lds16(Brow0, &smem[4096 + g0 * 8]);
  gl_lds16(Brow1, &smem[4096 + g1 * 8]);
  __syncthreads();

  for (int it = 0; it < 32; it++) {
    const int cur = (it & 1) * 8192;
    if (it + 1 < 32) {
      const int nxt = 8192 - cur;
      const int k1 = (it + 1) * 32;
      gl_lds16(Arow0 + k1, &smem[nxt + g0 * 8]);
      gl_lds16(Arow1 + k1, &smem[nxt + g1 * 8]);
      gl_lds16(Brow0 + k1, &smem[nxt + 4096 + g0 * 8]);
      gl_lds16(Brow1 + k1, &smem[nxt + 4096 + g1 * 8]);
    }
    const unsigned short* As = &smem[cur];
    const unsigned short* Bs = &smem[cur + 4096];

    bf16x8 af[4], bfr[4];
#pragma unroll
    for (int mt = 0; mt < 4; mt++)
      af[mt] = __builtin_bit_cast(
          bf16x8,
          *reinterpret_cast<const short8*>(&As[(wm + mt * 16 + lr) * 32 + (quad ^ rxor) * 8]));
#pragma unroll
    for (int nt = 0; nt < 4; nt++)
      bfr[nt] = __builtin_bit_cast(
          bf16x8,
          *reinterpret_cast<const short8*>(&Bs[(wn + nt * 16 + lr) * 32 + (quad ^ rxor) * 8]));
#pragma unroll
    for (int mt = 0; mt < 4; mt++)
#pragma unroll
      for (int nt = 0; nt < 4; nt++)
        acc[mt][nt] = __builtin_amdgcn_mfma_f32_16x16x32_bf16(af[mt], bfr[nt], acc[mt][nt], 0, 0, 0);
    __syncthreads();
  }

#pragma unroll
  for (int mt = 0; mt < 4; mt++) {
#pragma unroll
    for (int nt = 0; nt < 4; nt++) {
      int col = bn * 128 + wn + nt * 16 + lr;
#pragma unroll
      for (int r = 0; r < 4; r++) {
        int row = bm * 128 + wm + mt * 16 + quad * 4 + r;
        Cp[(size_t)row * N + col] = acc[mt][nt][r];
      }
    }
  }
}

// ---------------- causal flash attention v10 (round-12/13 proven, verbatim revert) ----------
__global__ __launch_bounds__(512, 4) void attn_causal(const unsigned short* __restrict__ Q,
                                                      const unsigned short* __restrict__ Km,
                                                      const unsigned short* __restrict__ Vt,
                                                      unsigned short* __restrict__ O) {
  __shared__ __align__(16) unsigned short Kv[2][2][64 * 64];  // [buf][K=0/V=1], unpadded
  __shared__ __align__(16) unsigned short Ps[8][16 * 72];

  const int bid = blockIdx.x;
  const int p = bid & 7;
  const int h = (bid >> 3) & 15;
  const int b = bid >> 7;

  const int t = threadIdx.x;
  const int wave = t >> 6, lane = t & 63;
  const int lr = lane & 15, quad = lane >> 4;
  const int cxor = lr & 7;

  const size_t base = (size_t)b * SEQ * D_MODEL + h * HEAD_DIM;
  const unsigned short* Qb = Q + base;
  const unsigned short* Kb = Km + base;
  const unsigned short* Vb = Vt + (size_t)(b * N_HEADS + h) * HEAD_DIM * SEQ;
  unsigned short* pw = &Ps[wave][0];

  const int srow = t >> 3;
  const int scol = ((t & 7) ^ (srow & 7)) << 3;
  const unsigned short* Kg = Kb + (size_t)srow * D_MODEL + scol;
  const unsigned short* Vg = Vb + (size_t)srow * SEQ + scol;

  for (int ph = 0; ph < 2; ph++) {
    const int qt = ph ? (15 - p) : p;
    const int m0 = qt * 128 + wave * 16;
    const int ntiles = (qt + 1) * 2;

    bf16x8 qf[2];
#pragma unroll
    for (int kk = 0; kk < 2; kk++)
      qf[kk] = __builtin_bit_cast(
          bf16x8,
          *reinterpret_cast<const short8*>(Qb + (size_t)(m0 + lr) * D_MODEL + kk * 32 + quad * 8));

    f32x4 o_acc[4] = {};
    float lsum[4] = {};

    gl_lds16(Kg, &Kv[0][0][t * 8]);
    gl_lds16(Vg, &Kv[0][1][t * 8]);

    for (int kt = 0; kt < ntiles; kt++) {
      const int cur = kt & 1;
      const int kv0 = kt * 64;
      __syncthreads();  // drains gl_lds into buf[cur]; orders buf[1-cur] reuse
      if (kt + 1 < ntiles) {
        gl_lds16(Kg + (size_t)(kv0 + 64) * D_MODEL, &Kv[1 - cur][0][t * 8]);
        gl_lds16(Vg + kv0 + 64, &Kv[1 - cur][1][t * 8]);
      }
      const unsigned short* Ks = &Kv[cur][0][0];
      const unsigned short* Vs = &Kv[cur][1][0];

      f32x4 sAcc[4] = {};
#pragma unroll
      for (int kk = 0; kk < 2; kk++) {
        bf16x8 kf[4];
#pragma unroll
        for (int j = 0; j < 4; j++)
          kf[j] = __builtin_bit_cast(
              bf16x8, *reinterpret_cast<const short8*>(
                          &Ks[(j * 16 + lr) * 64 + ((kk * 4 + quad) ^ cxor) * 8]));
#pragma unroll
        for (int j = 0; j < 4; j++)
          sAcc[j] = __builtin_amdgcn_mfma_f32_16x16x32_bf16(qf[kk], kf[j], sAcc[j], 0, 0, 0);
      }

      asm volatile("s_waitcnt lgkmcnt(0)" ::: "memory");  // prev pf reads drained
      const bool needmask = (kv0 + 63 > m0);              // wave-uniform
#pragma unroll
      for (int r = 0; r < 4; r++) {
        const int qpos = m0 + quad * 4 + r;
        float e[4];
#pragma unroll
        for (int j = 0; j < 4; j++) e[j] = EXP2F(sAcc[j][r]);
        if (needmask) {
#pragma unroll
          for (int j = 0; j < 4; j++)
            if (kv0 + j * 16 + lr > qpos) e[j] = 0.f;
        }
        lsum[r] += (e[0] + e[1]) + (e[2] + e[3]);
        unsigned short* pr = &pw[(quad * 4 + r) * 72];
#pragma unroll
        for (int j = 0; j < 4; j++) pr[j * 16 + lr] = f2bf_rne(e[j]);
      }
      asm volatile("s_waitcnt lgkmcnt(0)" ::: "memory");  // P writes visible (wave-lockstep)

#pragma unroll
      for (int kk = 0; kk < 2; kk++) {
        bf16x8 pf = __builtin_bit_cast(
            bf16x8, *reinterpret_cast<const short8*>(&pw[lr * 72 + kk * 32 + quad * 8]));
#pragma unroll
        for (int c = 0; c < 4; c++) {
          bf16x8 vv = __builtin_bit_cast(
              bf16x8, *reinterpret_cast<const short8*>(
                          &Vs[(c * 16 + lr) * 64 + ((kk * 4 + quad) ^ cxor) * 8]));
          o_acc[c] = __builtin_amdgcn_mfma_f32_16x16x32_bf16(pf, vv, o_acc[c], 0, 0, 0);
        }
      }
    }

#pragma unroll
    for (int r = 0; r < 4; r++) {
      float l = lsum[r];
#pragma unroll
      for (int off = 1; off < 16; off <<= 1) l += __shfl_xor(l, off, 64);
      const float inv = 1.f / l;
      const int qpos = m0 + quad * 4 + r;
#pragma unroll
      for (int c = 0; c < 4; c++)
        O[base + (size_t)qpos * D_MODEL + c * 16 + lr] = f2bf_rne(o_acc[c][r] * inv);
    }
  }
}

// ---------------- launch ----------------
extern "C" void kernel_launch(void* const* d_in, const int* in_sizes, int n_in,
                              void* d_out, int out_size, void* d_ws, size_t ws_size,
                              hipStream_t stream) {
  const float* x  = (const float*)d_in[0];
  const float* Wq = (const float*)d_in[1];
  const float* Wk = (const float*)d_in[2];
  const float* Wv = (const float*)d_in[3];
  const float* Wo = (const float*)d_in[4];
  float* out = (float*)d_out;

  char* ws = (char*)d_ws;
  const size_t SZ_X = (size_t)M_ROWS * D_MODEL * 2;   // 16 MB
  const size_t SZ_W = (size_t)D_MODEL * D_MODEL * 2;  //  2 MB
  unsigned short* xb  = (unsigned short*)(ws);
  unsigned short* wqb = (unsigned short*)(ws + SZ_X);
  unsigned short* wkb = (unsigned short*)(ws + SZ_X + 1 * SZ_W);
  unsigned short* wvb = (unsigned short*)(ws + SZ_X + 2 * SZ_W);
  unsigned short* wob = (unsigned short*)(ws + SZ_X + 3 * SZ_W);
  unsigned short* Qb  = (unsigned short*)(ws + 1 * SZ_X + 4 * SZ_W);
  unsigned short* Kb  = (unsigned short*)(ws + 2 * SZ_X + 4 * SZ_W);
  unsigned short* Vt  = (unsigned short*)(ws + 3 * SZ_X + 4 * SZ_W);
  unsigned short* Ob  = xb;  // x dead after QKV projection

  cvt_all<<<12288, 256, 0, stream>>>(x, Wq, Wk, Wv, Wo, xb, wqb, wkb, wvb, wob);

  qkv_gemm<<<dim3(24, 64), 256, 0, stream>>>(xb, wqb, wkb, wvb, Qb, Kb, Vt);

  attn_causal<<<512, 512, 0, stream>>>(Qb, Kb, Vt, Ob);

  gemm_bt_f32<<<dim3(8, 64), 256, 0, stream>>>(Ob, wob, out, M_ROWS, D_MODEL, D_MODEL);
}